// Round 5
// baseline (830.095 us; speedup 1.0000x reference)
//
#include <hip/hip_runtime.h>
#include <stdint.h>

#define NTOK  262144
#define HD    256
#define BM    64
#define NBLK  (NTOK / BM)   // 4096

typedef unsigned short u16;
typedef __attribute__((ext_vector_type(8))) short bfrag;   // 8 bf16 (4 VGPRs)
typedef __attribute__((ext_vector_type(4))) float facc;    // MFMA C/D
typedef __attribute__((ext_vector_type(4))) float f32x4v;

// ---- ws layout (bytes) ----
// w1t: bf16 fragment-major [s=kc*2+h2 (8)][nt (16)][cl (16)][q (4)][8]  = 131072 B
// wet: bf16 fragment-major [(e*8+s) (32)][c (256)][q (4)][8]            = 524288 B
#define WS_W1T    0
#define WS_WET    131072
#define WS_WCOMB  655360     // f32 [k=256][e=4]
#define WS_BCOMB  659456     // f32 [4]
#define WS_WCOMBT 659472     // f32 [e=4][k=256] (transposed copy for logits)
#define WS_FLAG   663568     // u64 prep-done magic
#define PREP_MAGIC 0x9e3779b97f4a7c15ull

static __device__ __forceinline__ u16 f2bf(float f) {  // fp32 -> bf16 RNE
  union { float f; uint32_t u; } v; v.f = f;
  uint32_t r = v.u + 0x7FFFu + ((v.u >> 16) & 1u);
  return (u16)(r >> 16);
}

// ---------- single prep kernel: swizzle W1/We to fragment layout + Wcomb ----------
__global__ __launch_bounds__(256)
void prep_all(const float* __restrict__ W1, const float* __restrict__ b1,
              const float* __restrict__ Wg, const float* __restrict__ We,
              u16* __restrict__ w1t, u16* __restrict__ wet,
              float* __restrict__ wcomb, float* __restrict__ bcomb,
              float* __restrict__ wcombT,
              const unsigned long long* __restrict__ flag) {
  if (*flag == PREP_MAGIC) return;
  const int b = blockIdx.x, t = threadIdx.x;
  if (b < 160) {
    int id = b * 256 + t;                 // one bf16x8 fragment per thread
    if (id < 8192) {
      int q = id & 3, cl = (id >> 2) & 15, nt = (id >> 6) & 15;
      int h2 = (id >> 10) & 1, kc = id >> 11;
      int k0 = kc * 64 + h2 * 32 + q * 8, c = nt * 16 + cl;
      bfrag v;
#pragma unroll
      for (int j = 0; j < 8; ++j) v[j] = (short)f2bf(W1[(size_t)(k0 + j) * 256 + c]);
      *(bfrag*)(w1t + (size_t)id * 8) = v;
    } else {
      int s = id - 8192;
      int q = s & 3, c = (s >> 2) & 255, h2 = (s >> 10) & 1;
      int kc = (s >> 11) & 3, e = s >> 13;
      int k0 = kc * 64 + h2 * 32 + q * 8;
      const float* Wep = We + (size_t)e * 65536;
      bfrag v;
#pragma unroll
      for (int j = 0; j < 8; ++j) v[j] = (short)f2bf(Wep[(size_t)(k0 + j) * 256 + c]);
      *(bfrag*)(wet + (size_t)s * 8) = v;
    }
  } else {
    // Wcomb = W1@Wg, bcomb = b1@Wg in fp64, one wave per output element
    int o = (b - 160) * 4 + (t >> 6);
    int l = t & 63;
    if (o < 1024) {
      int k = o >> 2, e = o & 3;
      double acc = 0.0;
#pragma unroll
      for (int i = 0; i < 4; ++i) {
        int m = l + 64 * i;
        acc += (double)W1[k * 256 + m] * (double)Wg[m * 4 + e];
      }
#pragma unroll
      for (int m = 32; m >= 1; m >>= 1) acc += __shfl_xor(acc, m, 64);
      if (l == 0) { wcomb[o] = (float)acc; wcombT[e * 256 + k] = (float)acc; }
    } else if (o < 1028) {
      int e = o - 1024;
      double acc = 0.0;
#pragma unroll
      for (int i = 0; i < 4; ++i) {
        int m = l + 64 * i;
        acc += (double)b1[m] * (double)Wg[m * 4 + e];
      }
#pragma unroll
      for (int m = 32; m >= 1; m >>= 1) acc += __shfl_xor(acc, m, 64);
      if (l == 0) bcomb[e] = (float)acc;
    }
  }
}

// ---------- fused MoE kernel: BM=64, 8 waves, lean regs -> 3 blocks/CU target ----
__global__ __launch_bounds__(512, 6)
void moe_fused(const float* __restrict__ x,
               const u16* __restrict__ w1t, const u16* __restrict__ wet,
               const float* __restrict__ wcombT, const float* __restrict__ bcomb,
               const float* __restrict__ b1, const float* __restrict__ be,
               float* __restrict__ out, unsigned long long* __restrict__ flag) {
  __shared__ u16   hs[BM][264];          // h tile bf16, +8 pad (33792 B)
  __shared__ float logits_s[BM][4];
  __shared__ float gate_s[BM];
  __shared__ int   pos_s[BM];
  __shared__ int   eidx_s[BM];
  __shared__ int   perm_s[BM];
  __shared__ int   cnt_s[4];
  __shared__ int   base_s[4];
  // total LDS ~35.9 KB -> 3 blocks/CU (if regs allow 6 waves/SIMD)

  const int t    = threadIdx.x;          // 0..511
  const int lane = t & 63;
  const int w    = t >> 6;               // 0..7
  const int cl   = lane & 15;
  const int q    = lane >> 4;
  const int tokbase = blockIdx.x * BM;

  if (blockIdx.x == 0 && t == 0) *flag = PREP_MAGIC;  // preps done (stream-ordered)

  if (t < 4) cnt_s[t] = 0;               // ordered by barrier after logits

  // ---- logits = x @ Wcomb + bcomb, fp64, 8 threads/token (half-k split) ----
  {
    const int tok  = t >> 3;             // 0..63
    const int sub  = t & 7;
    const int e    = sub & 3;
    const int half = sub >> 2;           // k in [half*128, half*128+128)
    const float* xr = x + (size_t)(tokbase + tok) * HD + half * 128;
    const float* wc = wcombT + e * 256 + half * 128;
    double a0 = 0.0, a1 = 0.0, a2 = 0.0, a3 = 0.0;
#pragma unroll
    for (int k = 0; k < 128; k += 32) {
      f32x4v xv[8];
#pragma unroll
      for (int j = 0; j < 8; ++j) xv[j] = *(const f32x4v*)(xr + k + 4 * j);
#pragma unroll
      for (int j = 0; j < 8; ++j) {
        f32x4v wv = *(const f32x4v*)(wc + k + 4 * j);
        a0 += (double)xv[j].x * (double)wv.x;
        a1 += (double)xv[j].y * (double)wv.y;
        a2 += (double)xv[j].z * (double)wv.z;
        a3 += (double)xv[j].w * (double)wv.w;
      }
    }
    // combine the two k-halves (thread pairs lane, lane^4) in fp64
    a0 += __shfl_xor(a0, 4, 64);
    a1 += __shfl_xor(a1, 4, 64);
    a2 += __shfl_xor(a2, 4, 64);
    a3 += __shfl_xor(a3, 4, 64);
    if (half == 0)
      logits_s[tok][e] = (float)(((a0 + a1) + (a2 + a3)) + (double)bcomb[e]);
  }
  __syncthreads();

  // ---- softmax / argmax / block-local counting sort ----
  if (t < BM) {
    float l0 = logits_s[t][0], l1 = logits_s[t][1];
    float l2 = logits_s[t][2], l3 = logits_s[t][3];
    float m = fmaxf(fmaxf(l0, l1), fmaxf(l2, l3));
    float s = __expf(l0 - m) + __expf(l1 - m) + __expf(l2 - m) + __expf(l3 - m);
    int e = 0; float bl = l0;
    if (l1 > bl) { bl = l1; e = 1; }
    if (l2 > bl) { bl = l2; e = 2; }
    if (l3 > bl) { bl = l3; e = 3; }
    gate_s[t] = 1.0f / s;
    eidx_s[t] = e;
    pos_s[t]  = atomicAdd(&cnt_s[e], 1);
  }
  __syncthreads();
  if (t == 0) {
    int b = 0;
#pragma unroll
    for (int e = 0; e < 4; ++e) { base_s[e] = b; b += cnt_s[e]; }
  }
  __syncthreads();
  if (t < BM) perm_s[base_s[eidx_s[t]] + pos_s[t]] = t;
  // (visible after the post-hs barrier below)

  // ---- stage 1: h = x @ W1, B direct from global (L2-hot), 2x4 wave split ----
  // wave w: rows [ (w>>2)*32, +32 ), cols [ (w&3)*64, +64 )
  const int rw = w >> 2, wc4 = w & 3;
  facc acc1[2][4];
#pragma unroll
  for (int m = 0; m < 2; ++m)
#pragma unroll
    for (int nt = 0; nt < 4; ++nt) acc1[m][nt] = (facc){0.f, 0.f, 0.f, 0.f};

  const float* xrow0 = x + (size_t)(tokbase + rw * 32 + cl) * HD;
  const float* xrow1 = xrow0 + 16 * HD;

#pragma unroll
  for (int kc = 0; kc < 4; ++kc) {
#pragma unroll
    for (int h2 = 0; h2 < 2; ++h2) {
      const int k0 = kc * 64 + h2 * 32 + q * 8;
      f32x4v xa0 = *(const f32x4v*)(xrow0 + k0);
      f32x4v xb0 = *(const f32x4v*)(xrow0 + k0 + 4);
      f32x4v xa1 = *(const f32x4v*)(xrow1 + k0);
      f32x4v xb1 = *(const f32x4v*)(xrow1 + k0 + 4);
      bfrag a0, a1;
      a0[0] = (short)f2bf(xa0.x); a0[1] = (short)f2bf(xa0.y);
      a0[2] = (short)f2bf(xa0.z); a0[3] = (short)f2bf(xa0.w);
      a0[4] = (short)f2bf(xb0.x); a0[5] = (short)f2bf(xb0.y);
      a0[6] = (short)f2bf(xb0.z); a0[7] = (short)f2bf(xb0.w);
      a1[0] = (short)f2bf(xa1.x); a1[1] = (short)f2bf(xa1.y);
      a1[2] = (short)f2bf(xa1.z); a1[3] = (short)f2bf(xa1.w);
      a1[4] = (short)f2bf(xb1.x); a1[5] = (short)f2bf(xb1.y);
      a1[6] = (short)f2bf(xb1.z); a1[7] = (short)f2bf(xb1.w);
      const u16* bp = w1t + (size_t)(kc * 2 + h2) * 8192
                          + (size_t)(wc4 * 4) * 512 + (cl * 4 + q) * 8;
#pragma unroll
      for (int nt = 0; nt < 4; ++nt) {
        bfrag bfr = *(const bfrag*)(bp + nt * 512);
        acc1[0][nt] = __builtin_amdgcn_mfma_f32_16x16x32_bf16(a0, bfr, acc1[0][nt], 0, 0, 0);
        acc1[1][nt] = __builtin_amdgcn_mfma_f32_16x16x32_bf16(a1, bfr, acc1[1][nt], 0, 0, 0);
      }
    }
  }
  // write h (+b1) to LDS as bf16
#pragma unroll
  for (int m = 0; m < 2; ++m)
#pragma unroll
    for (int nt = 0; nt < 4; ++nt) {
      const int c = wc4 * 64 + nt * 16 + cl;
      const float bb = b1[c];
#pragma unroll
      for (int r = 0; r < 4; ++r)
        hs[rw * 32 + m * 16 + q * 4 + r][c] = f2bf(acc1[m][nt][r] + bb);
    }
  __syncthreads();

  // ---- stage 2: per-expert GEMM, B direct from global, 32 cols per wave ----
  const u16* wetw = wet + (size_t)w * 1024 + (size_t)(cl * 4 + q) * 8;
  bfrag pf0 = *(const bfrag*)(wetw);          // flattened (e,s)=0 prefetch
  bfrag pf1 = *(const bfrag*)(wetw + 512);
  for (int e = 0; e < 4; ++e) {
    const int cnt  = cnt_s[e];             // block-uniform
    const int ng   = (cnt + 15) >> 4;      // <= 4
    const int base = base_s[e];

    int  prow_r[4];
    bool val_r[4];
#pragma unroll
    for (int g = 0; g < 4; ++g) {
      const int rowi = g * 16 + cl;
      const bool v = rowi < cnt;
      val_r[g]  = v;
      prow_r[g] = perm_s[base + (v ? rowi : 0)];
    }

    facc acc2[4][2];
#pragma unroll
    for (int g = 0; g < 4; ++g) {
      acc2[g][0] = (facc){0.f, 0.f, 0.f, 0.f};
      acc2[g][1] = (facc){0.f, 0.f, 0.f, 0.f};
    }

#pragma unroll
    for (int s = 0; s < 8; ++s) {
      const int k0 = s * 32 + q * 8;
      bfrag wf0 = pf0, wf1 = pf1;
      const int f = e * 8 + s;
      if (f < 31) {                         // prefetch next flattened step
        pf0 = *(const bfrag*)(wetw + (size_t)(f + 1) * 8192);
        pf1 = *(const bfrag*)(wetw + (size_t)(f + 1) * 8192 + 512);
      }
#pragma unroll
      for (int g = 0; g < 4; ++g) {
        if (g < ng) {
          bfrag a = *(const bfrag*)&hs[prow_r[g]][k0];
          if (!val_r[g]) { bfrag z = {0,0,0,0,0,0,0,0}; a = z; }
          acc2[g][0] = __builtin_amdgcn_mfma_f32_16x16x32_bf16(a, wf0, acc2[g][0], 0, 0, 0);
          acc2[g][1] = __builtin_amdgcn_mfma_f32_16x16x32_bf16(a, wf1, acc2[g][1], 0, 0, 0);
        }
      }
    }
    // epilogue: out = gate * (acc + be[e])
#pragma unroll
    for (int n4 = 0; n4 < 2; ++n4) {
      const int c = w * 32 + n4 * 16 + cl;
      const float bev = be[e * 256 + c];
#pragma unroll
      for (int g = 0; g < 4; ++g) {
        if (g < ng) {
#pragma unroll
          for (int r = 0; r < 4; ++r) {
            const int rowi = g * 16 + q * 4 + r;
            if (rowi < cnt) {
              const int tok = perm_s[base + rowi];
              out[(size_t)(tokbase + tok) * HD + c] = gate_s[tok] * (acc2[g][n4][r] + bev);
            }
          }
        }
      }
    }
  }
}

extern "C" void kernel_launch(void* const* d_in, const int* in_sizes, int n_in,
                              void* d_out, int out_size, void* d_ws, size_t ws_size,
                              hipStream_t stream) {
  const float* x  = (const float*)d_in[0];
  const float* W1 = (const float*)d_in[1];
  const float* b1 = (const float*)d_in[2];
  const float* Wg = (const float*)d_in[3];
  const float* We = (const float*)d_in[4];
  const float* be = (const float*)d_in[5];
  float* out = (float*)d_out;

  char* ws = (char*)d_ws;
  u16*   w1t    = (u16*)(ws + WS_W1T);
  u16*   wet    = (u16*)(ws + WS_WET);
  float* wcomb  = (float*)(ws + WS_WCOMB);
  float* bcomb  = (float*)(ws + WS_BCOMB);
  float* wcombT = (float*)(ws + WS_WCOMBT);
  unsigned long long* flag = (unsigned long long*)(ws + WS_FLAG);

  prep_all <<<417, 256, 0, stream>>>(W1, b1, Wg, We, w1t, wet, wcomb, bcomb, wcombT, flag);
  moe_fused<<<NBLK, 512, 0, stream>>>(x, w1t, wet, wcombT, bcomb, b1, be, out, flag);
}

// Round 6
// 742.819 us; speedup vs baseline: 1.1175x; 1.1175x over previous
//
#include <hip/hip_runtime.h>
#include <stdint.h>

#define NTOK  262144
#define HD    256
#define BM    128
#define NBLK  (NTOK / BM)   // 2048

typedef unsigned short u16;
typedef __attribute__((ext_vector_type(8))) short bfrag;   // 8 bf16 (4 VGPRs)
typedef __attribute__((ext_vector_type(4))) float facc;    // MFMA C/D
typedef __attribute__((ext_vector_type(4))) float f32x4v;

// ---- ws layout (bytes) ----
// w1t: bf16 fragment-major [s=kc*2+h2 (8)][nt (16)][cl (16)][q (4)][8]  = 131072 B
// wet: bf16 fragment-major [(e*4+kc)*2+h2 (32)][c (256)][q (4)][8]      = 524288 B
#define WS_W1T   0
#define WS_WET   131072
#define WS_WCOMB 655360     // f32 [k=256][e=4]
#define WS_BCOMB 659456     // f32 [4]
#define WS_FLAG  659472     // u64 prep-done magic
#define PREP_MAGIC 0x9e3779b97f4a7c15ull

static __device__ __forceinline__ u16 f2bf(float f) {  // fp32 -> bf16 RNE
  union { float f; uint32_t u; } v; v.f = f;
  uint32_t r = v.u + 0x7FFFu + ((v.u >> 16) & 1u);
  return (u16)(r >> 16);
}

// ---------- single prep kernel: swizzle W1/We to fragment layout + Wcomb ----------
__global__ __launch_bounds__(256)
void prep_all(const float* __restrict__ W1, const float* __restrict__ b1,
              const float* __restrict__ Wg, const float* __restrict__ We,
              u16* __restrict__ w1t, u16* __restrict__ wet,
              float* __restrict__ wcomb, float* __restrict__ bcomb,
              const unsigned long long* __restrict__ flag) {
  if (*flag == PREP_MAGIC) return;
  const int b = blockIdx.x, t = threadIdx.x;
  if (b < 160) {
    int id = b * 256 + t;                 // one bf16x8 fragment per thread
    if (id < 8192) {
      int q = id & 3, cl = (id >> 2) & 15, nt = (id >> 6) & 15;
      int h2 = (id >> 10) & 1, kc = id >> 11;
      int k0 = kc * 64 + h2 * 32 + q * 8, c = nt * 16 + cl;
      bfrag v;
#pragma unroll
      for (int j = 0; j < 8; ++j) v[j] = (short)f2bf(W1[(size_t)(k0 + j) * 256 + c]);
      *(bfrag*)(w1t + (size_t)id * 8) = v;
    } else {
      int s = id - 8192;
      int q = s & 3, c = (s >> 2) & 255, h2 = (s >> 10) & 1;
      int kc = (s >> 11) & 3, e = s >> 13;
      int k0 = kc * 64 + h2 * 32 + q * 8;
      const float* Wep = We + (size_t)e * 65536;
      bfrag v;
#pragma unroll
      for (int j = 0; j < 8; ++j) v[j] = (short)f2bf(Wep[(size_t)(k0 + j) * 256 + c]);
      *(bfrag*)(wet + (size_t)s * 8) = v;
    }
  } else {
    // Wcomb = W1@Wg, bcomb = b1@Wg in fp64, one wave per output element
    int o = (b - 160) * 4 + (t >> 6);
    int l = t & 63;
    if (o < 1024) {
      int k = o >> 2, e = o & 3;
      double acc = 0.0;
#pragma unroll
      for (int i = 0; i < 4; ++i) {
        int m = l + 64 * i;
        acc += (double)W1[k * 256 + m] * (double)Wg[m * 4 + e];
      }
#pragma unroll
      for (int m = 32; m >= 1; m >>= 1) acc += __shfl_xor(acc, m, 64);
      if (l == 0) wcomb[o] = (float)acc;
    } else if (o < 1028) {
      int e = o - 1024;
      double acc = 0.0;
#pragma unroll
      for (int i = 0; i < 4; ++i) {
        int m = l + 64 * i;
        acc += (double)b1[m] * (double)Wg[m * 4 + e];
      }
#pragma unroll
      for (int m = 32; m >= 1; m >>= 1) acc += __shfl_xor(acc, m, 64);
      if (l == 0) bcomb[e] = (float)acc;
    }
  }
}

// ---------- fused MoE: BM=128, 8 waves; logits fused INTO stage-1 phase ----------
__global__ __launch_bounds__(512, 4)
void moe_fused(const float* __restrict__ x,
               const u16* __restrict__ w1t, const u16* __restrict__ wet,
               const float* __restrict__ wcomb, const float* __restrict__ bcomb,
               const float* __restrict__ b1, const float* __restrict__ be,
               float* __restrict__ out, unsigned long long* __restrict__ flag) {
  __shared__ u16   hs[BM][264];          // h tile bf16, +8 pad (67584 B)
  __shared__ float logits_s[BM][4];
  __shared__ float gate_s[BM];
  __shared__ int   pos_s[BM];
  __shared__ int   eidx_s[BM];
  __shared__ int   perm_s[BM];
  __shared__ int   cnt_s[4];
  __shared__ int   base_s[4];
  // total LDS ~72 KB -> 2 blocks/CU, 16 waves/CU

  const int t    = threadIdx.x;          // 0..511
  const int lane = t & 63;
  const int w    = t >> 6;               // 0..7
  const int cl   = lane & 15;
  const int q    = lane >> 4;
  const int tokbase = blockIdx.x * BM;

  if (blockIdx.x == 0 && t == 0) *flag = PREP_MAGIC;  // preps done (stream-ordered)
  if (t < 4) cnt_s[t] = 0;               // ordered by phase-A barrier

  // ---- phase A: stage 1 (h = x @ W1, MFMA) fused with logits (fp64 dot) ----
  // logits: thread (ltok = t>>2, kq = t&3) covers k in [kq*64, kq*64+64);
  // x row read ONCE per thread (vs 4x in the phase-split version).
  const int ltok = t >> 2, kq = t & 3;
  const float* lxr = x + (size_t)(tokbase + ltok) * HD + kq * 64;
  double la0 = 0.0, la1 = 0.0, la2 = 0.0, la3 = 0.0;

  // stage-1 wave split: rows [ (w>>1)*32, +32 ), cols [ (w&1)*128, +128 )
  const int rw = w >> 1, wc2 = w & 1;
  facc acc1[2][8];
#pragma unroll
  for (int m = 0; m < 2; ++m)
#pragma unroll
    for (int nt = 0; nt < 8; ++nt) acc1[m][nt] = (facc){0.f, 0.f, 0.f, 0.f};

  const float* xrow0 = x + (size_t)(tokbase + rw * 32 + cl) * HD;
  const float* xrow1 = xrow0 + 16 * HD;

#pragma unroll
  for (int kc = 0; kc < 4; ++kc) {
#pragma unroll
    for (int h2 = 0; h2 < 2; ++h2) {
      // -- logits sub-step: 8 k-elements, loads fly under the MFMAs below --
      const int lk = (kc * 2 + h2) * 8;
      f32x4v lx0 = *(const f32x4v*)(lxr + lk);
      f32x4v lx1 = *(const f32x4v*)(lxr + lk + 4);
      const float* wp = wcomb + (size_t)(kq * 64 + lk) * 4;

      // -- stage-1 A-fragment loads + pack --
      const int k0 = kc * 64 + h2 * 32 + q * 8;
      f32x4v xa0 = *(const f32x4v*)(xrow0 + k0);
      f32x4v xb0 = *(const f32x4v*)(xrow0 + k0 + 4);
      f32x4v xa1 = *(const f32x4v*)(xrow1 + k0);
      f32x4v xb1 = *(const f32x4v*)(xrow1 + k0 + 4);
      bfrag a0, a1;
      a0[0] = (short)f2bf(xa0.x); a0[1] = (short)f2bf(xa0.y);
      a0[2] = (short)f2bf(xa0.z); a0[3] = (short)f2bf(xa0.w);
      a0[4] = (short)f2bf(xb0.x); a0[5] = (short)f2bf(xb0.y);
      a0[6] = (short)f2bf(xb0.z); a0[7] = (short)f2bf(xb0.w);
      a1[0] = (short)f2bf(xa1.x); a1[1] = (short)f2bf(xa1.y);
      a1[2] = (short)f2bf(xa1.z); a1[3] = (short)f2bf(xa1.w);
      a1[4] = (short)f2bf(xb1.x); a1[5] = (short)f2bf(xb1.y);
      a1[6] = (short)f2bf(xb1.z); a1[7] = (short)f2bf(xb1.w);

      const u16* bp = w1t + (size_t)(kc * 2 + h2) * 8192
                          + (size_t)(wc2 * 8) * 512 + (cl * 4 + q) * 8;
#pragma unroll
      for (int nt = 0; nt < 8; ++nt) {
        bfrag bfr = *(const bfrag*)(bp + nt * 512);
        acc1[0][nt] = __builtin_amdgcn_mfma_f32_16x16x32_bf16(a0, bfr, acc1[0][nt], 0, 0, 0);
        acc1[1][nt] = __builtin_amdgcn_mfma_f32_16x16x32_bf16(a1, bfr, acc1[1][nt], 0, 0, 0);
      }

      // -- logits fp64 FMAs (VALU pipe, overlaps MFMA pipe) --
#pragma unroll
      for (int j = 0; j < 4; ++j) {
        f32x4v wv = *(const f32x4v*)(wp + j * 4);
        double xj = (double)lx0[j];
        la0 += xj * (double)wv.x; la1 += xj * (double)wv.y;
        la2 += xj * (double)wv.z; la3 += xj * (double)wv.w;
      }
#pragma unroll
      for (int j = 0; j < 4; ++j) {
        f32x4v wv = *(const f32x4v*)(wp + 16 + j * 4);
        double xj = (double)lx1[j];
        la0 += xj * (double)wv.x; la1 += xj * (double)wv.y;
        la2 += xj * (double)wv.z; la3 += xj * (double)wv.w;
      }
    }
  }

  // combine logits across the 4 k-quarter lanes (fp64 -> flip-safe)
  la0 += __shfl_xor(la0, 1, 64); la0 += __shfl_xor(la0, 2, 64);
  la1 += __shfl_xor(la1, 1, 64); la1 += __shfl_xor(la1, 2, 64);
  la2 += __shfl_xor(la2, 1, 64); la2 += __shfl_xor(la2, 2, 64);
  la3 += __shfl_xor(la3, 1, 64); la3 += __shfl_xor(la3, 2, 64);
  if (kq == 0) {
    logits_s[ltok][0] = (float)(la0 + (double)bcomb[0]);
    logits_s[ltok][1] = (float)(la1 + (double)bcomb[1]);
    logits_s[ltok][2] = (float)(la2 + (double)bcomb[2]);
    logits_s[ltok][3] = (float)(la3 + (double)bcomb[3]);
  }

  // write h (+b1) to LDS as bf16
#pragma unroll
  for (int m = 0; m < 2; ++m)
#pragma unroll
    for (int nt = 0; nt < 8; ++nt) {
      const int c = wc2 * 128 + nt * 16 + cl;
      const float bb = b1[c];
#pragma unroll
      for (int r = 0; r < 4; ++r)
        hs[rw * 32 + m * 16 + q * 4 + r][c] = f2bf(acc1[m][nt][r] + bb);
    }
  __syncthreads();

  // ---- phase B: softmax / argmax / block-local counting sort ----
  if (t < BM) {
    float l0 = logits_s[t][0], l1 = logits_s[t][1];
    float l2 = logits_s[t][2], l3 = logits_s[t][3];
    float m = fmaxf(fmaxf(l0, l1), fmaxf(l2, l3));
    float s = __expf(l0 - m) + __expf(l1 - m) + __expf(l2 - m) + __expf(l3 - m);
    int e = 0; float bl = l0;
    if (l1 > bl) { bl = l1; e = 1; }
    if (l2 > bl) { bl = l2; e = 2; }
    if (l3 > bl) { bl = l3; e = 3; }
    gate_s[t] = 1.0f / s;
    eidx_s[t] = e;
    pos_s[t]  = atomicAdd(&cnt_s[e], 1);
  }
  __syncthreads();
  if (t == 0) {
    int b = 0;
#pragma unroll
    for (int e = 0; e < 4; ++e) { base_s[e] = b; b += cnt_s[e]; }
  }
  __syncthreads();
  if (t < BM) perm_s[base_s[eidx_s[t]] + pos_s[t]] = t;
  __syncthreads();

  // ---- phase C: per-expert GEMM, B direct from global, 32 cols per wave ----
  for (int e = 0; e < 4; ++e) {
    const int cnt = cnt_s[e];              // block-uniform
    if (cnt == 0) continue;
    const int ng   = (cnt + 15) >> 4;      // <= 8
    const int base = base_s[e];

    int  prow_r[8];
    bool val_r[8];
#pragma unroll
    for (int g = 0; g < 8; ++g) {
      const int rowi = g * 16 + cl;
      const bool v = rowi < cnt;
      val_r[g]  = v;
      prow_r[g] = perm_s[base + (v ? rowi : 0)];
    }

    facc acc2[8][2];
#pragma unroll
    for (int g = 0; g < 8; ++g) {
      acc2[g][0] = (facc){0.f, 0.f, 0.f, 0.f};
      acc2[g][1] = (facc){0.f, 0.f, 0.f, 0.f};
    }

#pragma unroll
    for (int kc = 0; kc < 4; ++kc) {
#pragma unroll
      for (int h2 = 0; h2 < 2; ++h2) {
        const int k0 = kc * 64 + h2 * 32 + q * 8;
        const u16* bp = wet + (size_t)((e * 4 + kc) * 2 + h2) * 8192
                            + (size_t)(w * 2) * 512 + (cl * 4 + q) * 8;
        bfrag bf0 = *(const bfrag*)(bp);
        bfrag bf1 = *(const bfrag*)(bp + 512);
#pragma unroll
        for (int g = 0; g < 8; ++g) {
          if (g < ng) {
            bfrag a = *(const bfrag*)&hs[prow_r[g]][k0];
            if (!val_r[g]) { bfrag z = {0,0,0,0,0,0,0,0}; a = z; }
            acc2[g][0] = __builtin_amdgcn_mfma_f32_16x16x32_bf16(a, bf0, acc2[g][0], 0, 0, 0);
            acc2[g][1] = __builtin_amdgcn_mfma_f32_16x16x32_bf16(a, bf1, acc2[g][1], 0, 0, 0);
          }
        }
      }
    }
    // epilogue: out = gate * (acc + be[e]); n4 innermost so the two 64B
    // halves of each 128B out-line are stored back-to-back (write-combine).
    const float bev0 = be[e * 256 + w * 32 + cl];
    const float bev1 = be[e * 256 + w * 32 + 16 + cl];
#pragma unroll
    for (int g = 0; g < 8; ++g) {
      if (g < ng) {
#pragma unroll
        for (int r = 0; r < 4; ++r) {
          const int rowi = g * 16 + q * 4 + r;
          if (rowi < cnt) {
            const int tok = perm_s[base + rowi];
            const float gate = gate_s[tok];
            float* orow = out + (size_t)(tokbase + tok) * HD + w * 32 + cl;
            orow[0]  = gate * (acc2[g][0][r] + bev0);
            orow[16] = gate * (acc2[g][1][r] + bev1);
          }
        }
      }
    }
  }
}

extern "C" void kernel_launch(void* const* d_in, const int* in_sizes, int n_in,
                              void* d_out, int out_size, void* d_ws, size_t ws_size,
                              hipStream_t stream) {
  const float* x  = (const float*)d_in[0];
  const float* W1 = (const float*)d_in[1];
  const float* b1 = (const float*)d_in[2];
  const float* Wg = (const float*)d_in[3];
  const float* We = (const float*)d_in[4];
  const float* be = (const float*)d_in[5];
  float* out = (float*)d_out;

  char* ws = (char*)d_ws;
  u16*   w1t   = (u16*)(ws + WS_W1T);
  u16*   wet   = (u16*)(ws + WS_WET);
  float* wcomb = (float*)(ws + WS_WCOMB);
  float* bcomb = (float*)(ws + WS_BCOMB);
  unsigned long long* flag = (unsigned long long*)(ws + WS_FLAG);

  prep_all <<<417, 256, 0, stream>>>(W1, b1, Wg, We, w1t, wet, wcomb, bcomb, flag);
  moe_fused<<<NBLK, 512, 0, stream>>>(x, w1t, wet, wcomb, bcomb, b1, be, out, flag);
}

// Round 7
// 607.174 us; speedup vs baseline: 1.3671x; 1.2234x over previous
//
#include <hip/hip_runtime.h>
#include <stdint.h>

#define NTOK  262144
#define HD    256
#define BM    128
#define NBLK  (NTOK / BM)   // 2048

typedef unsigned short u16;
typedef unsigned int   u32;
typedef __attribute__((ext_vector_type(8))) short bfrag;   // 8 bf16 (4 VGPRs)
typedef __attribute__((ext_vector_type(4))) float facc;    // MFMA C/D
typedef __attribute__((ext_vector_type(4))) float f32x4v;
typedef __attribute__((ext_vector_type(2))) unsigned int u32x2;

// ---- ws layout (bytes) ----
// w1t: bf16 fragment-major [s=kc*2+h2 (8)][nt (16)][cl (16)][q (4)][8]  = 131072 B
// wet: bf16 fragment-major [(e*4+kc)*2+h2 (32)][c (256)][q (4)][8]      = 524288 B
#define WS_W1T   0
#define WS_WET   131072
#define WS_WCOMB 655360     // f32 [k=256][e=4]
#define WS_BCOMB 659456     // f32 [4]
#define WS_FLAG  659472     // u64 prep-done magic
#define PREP_MAGIC 0x9e3779b97f4a7c15ull

static __device__ __forceinline__ u16 f2bf(float f) {  // fp32 -> bf16 RNE
  union { float f; uint32_t u; } v; v.f = f;
  uint32_t r = v.u + 0x7FFFu + ((v.u >> 16) & 1u);
  return (u16)(r >> 16);
}

// ---------- single prep kernel: swizzle W1/We to fragment layout + Wcomb ----------
__global__ __launch_bounds__(256)
void prep_all(const float* __restrict__ W1, const float* __restrict__ b1,
              const float* __restrict__ Wg, const float* __restrict__ We,
              u16* __restrict__ w1t, u16* __restrict__ wet,
              float* __restrict__ wcomb, float* __restrict__ bcomb,
              const unsigned long long* __restrict__ flag) {
  if (*flag == PREP_MAGIC) return;
  const int b = blockIdx.x, t = threadIdx.x;
  if (b < 160) {
    int id = b * 256 + t;                 // one bf16x8 fragment per thread
    if (id < 8192) {
      int q = id & 3, cl = (id >> 2) & 15, nt = (id >> 6) & 15;
      int h2 = (id >> 10) & 1, kc = id >> 11;
      int k0 = kc * 64 + h2 * 32 + q * 8, c = nt * 16 + cl;
      bfrag v;
#pragma unroll
      for (int j = 0; j < 8; ++j) v[j] = (short)f2bf(W1[(size_t)(k0 + j) * 256 + c]);
      *(bfrag*)(w1t + (size_t)id * 8) = v;
    } else {
      int s = id - 8192;
      int q = s & 3, c = (s >> 2) & 255, h2 = (s >> 10) & 1;
      int kc = (s >> 11) & 3, e = s >> 13;
      int k0 = kc * 64 + h2 * 32 + q * 8;
      const float* Wep = We + (size_t)e * 65536;
      bfrag v;
#pragma unroll
      for (int j = 0; j < 8; ++j) v[j] = (short)f2bf(Wep[(size_t)(k0 + j) * 256 + c]);
      *(bfrag*)(wet + (size_t)s * 8) = v;
    }
  } else {
    // Wcomb = W1@Wg, bcomb = b1@Wg in fp64, one wave per output element
    int o = (b - 160) * 4 + (t >> 6);
    int l = t & 63;
    if (o < 1024) {
      int k = o >> 2, e = o & 3;
      double acc = 0.0;
#pragma unroll
      for (int i = 0; i < 4; ++i) {
        int m = l + 64 * i;
        acc += (double)W1[k * 256 + m] * (double)Wg[m * 4 + e];
      }
#pragma unroll
      for (int m = 32; m >= 1; m >>= 1) acc += __shfl_xor(acc, m, 64);
      if (l == 0) wcomb[o] = (float)acc;
    } else if (o < 1028) {
      int e = o - 1024;
      double acc = 0.0;
#pragma unroll
      for (int i = 0; i < 4; ++i) {
        int m = l + 64 * i;
        acc += (double)b1[m] * (double)Wg[m * 4 + e];
      }
#pragma unroll
      for (int m = 32; m >= 1; m >>= 1) acc += __shfl_xor(acc, m, 64);
      if (l == 0) bcomb[e] = (float)acc;
    }
  }
}

// ---------- fused MoE kernel: BM=128, 8 waves, transposed-output MFMA ----------
__global__ __launch_bounds__(512, 4)
void moe_fused(const float* __restrict__ x,
               const u16* __restrict__ w1t, const u16* __restrict__ wet,
               const float* __restrict__ wcomb, const float* __restrict__ bcomb,
               const float* __restrict__ b1, const float* __restrict__ be,
               float* __restrict__ out, unsigned long long* __restrict__ flag) {
  __shared__ u16   hs[BM][264];          // h tile bf16, +8 pad (67584 B); wcT aliased
  __shared__ float logits_s[BM][4];
  __shared__ float gate_s[BM];
  __shared__ int   pos_s[BM];
  __shared__ int   eidx_s[BM];
  __shared__ int   perm_s[BM];
  __shared__ int   cnt_s[4];
  __shared__ int   base_s[4];
  // total LDS ~71.8 KB -> 2 blocks/CU, 16 waves/CU

  const int t    = threadIdx.x;          // 0..511
  const int lane = t & 63;
  const int w    = t >> 6;               // 0..7
  const int cl   = lane & 15;
  const int q    = lane >> 4;
  const int tokbase = blockIdx.x * BM;

  if (blockIdx.x == 0 && t == 0) *flag = PREP_MAGIC;  // preps done (stream-ordered)

  float* wcT = (float*)&hs[0][0];        // [4][260] f32, alias (dead before hs write)

  // ---- init small LDS ----
  if (t < 4) cnt_s[t] = 0;
#pragma unroll
  for (int i = 0; i < 2; ++i) {
    int idx = i * 512 + t;
    wcT[(idx & 3) * 260 + (idx >> 2)] = wcomb[idx];
  }
  __syncthreads();

  // ---- logits = x @ Wcomb + bcomb, fp64 accumulation (flip-proof) ----
  // (verified R2 pattern: wave covers 16 tokens, quad-broadcast x reads)
  {
    const int tok = t >> 2, e = t & 3;
    const float* xr = x + (size_t)(tokbase + tok) * HD;
    const float* wc = wcT + e * 260;
    double a0 = 0.0, a1 = 0.0, a2 = 0.0, a3 = 0.0;
    for (int k = 0; k < HD; k += 32) {
      f32x4v xv[8];
#pragma unroll
      for (int j = 0; j < 8; ++j) xv[j] = *(const f32x4v*)(xr + k + 4 * j);
#pragma unroll
      for (int j = 0; j < 8; ++j) {
        f32x4v wv = *(const f32x4v*)(wc + k + 4 * j);
        a0 += (double)xv[j].x * (double)wv.x;
        a1 += (double)xv[j].y * (double)wv.y;
        a2 += (double)xv[j].z * (double)wv.z;
        a3 += (double)xv[j].w * (double)wv.w;
      }
    }
    logits_s[tok][e] = (float)(((a0 + a1) + (a2 + a3)) + (double)bcomb[e]);
  }
  __syncthreads();

  // ---- softmax / argmax / block-local counting sort ----
  if (t < BM) {
    float l0 = logits_s[t][0], l1 = logits_s[t][1];
    float l2 = logits_s[t][2], l3 = logits_s[t][3];
    float m = fmaxf(fmaxf(l0, l1), fmaxf(l2, l3));
    float s = __expf(l0 - m) + __expf(l1 - m) + __expf(l2 - m) + __expf(l3 - m);
    int e = 0; float bl = l0;
    if (l1 > bl) { bl = l1; e = 1; }
    if (l2 > bl) { bl = l2; e = 2; }
    if (l3 > bl) { bl = l3; e = 3; }
    gate_s[t] = 1.0f / s;
    eidx_s[t] = e;
    pos_s[t]  = atomicAdd(&cnt_s[e], 1);
  }
  __syncthreads();
  if (t == 0) {
    int b = 0;
#pragma unroll
    for (int e = 0; e < 4; ++e) { base_s[e] = b; b += cnt_s[e]; }
  }
  __syncthreads();
  if (t < BM) perm_s[base_s[eidx_s[t]] + pos_s[t]] = t;
  // (visible after the post-hs barrier below)

  // ---- stage 1: h = x @ W1, SWAPPED operands -> lane holds 4 consecutive h cols
  // wave w: rows [ (w>>1)*32, +32 ), cols [ (w&1)*128, +128 )
  const int rw = w >> 1, wc2 = w & 1;
  facc acc1[2][8];
#pragma unroll
  for (int m = 0; m < 2; ++m)
#pragma unroll
    for (int nt = 0; nt < 8; ++nt) acc1[m][nt] = (facc){0.f, 0.f, 0.f, 0.f};

  const float* xrow0 = x + (size_t)(tokbase + rw * 32 + cl) * HD;
  const float* xrow1 = xrow0 + 16 * HD;

#pragma unroll
  for (int kc = 0; kc < 4; ++kc) {
#pragma unroll
    for (int h2 = 0; h2 < 2; ++h2) {
      const int k0 = kc * 64 + h2 * 32 + q * 8;
      f32x4v xa0 = *(const f32x4v*)(xrow0 + k0);
      f32x4v xb0 = *(const f32x4v*)(xrow0 + k0 + 4);
      f32x4v xa1 = *(const f32x4v*)(xrow1 + k0);
      f32x4v xb1 = *(const f32x4v*)(xrow1 + k0 + 4);
      bfrag a0, a1;
      a0[0] = (short)f2bf(xa0.x); a0[1] = (short)f2bf(xa0.y);
      a0[2] = (short)f2bf(xa0.z); a0[3] = (short)f2bf(xa0.w);
      a0[4] = (short)f2bf(xb0.x); a0[5] = (short)f2bf(xb0.y);
      a0[6] = (short)f2bf(xb0.z); a0[7] = (short)f2bf(xb0.w);
      a1[0] = (short)f2bf(xa1.x); a1[1] = (short)f2bf(xa1.y);
      a1[2] = (short)f2bf(xa1.z); a1[3] = (short)f2bf(xa1.w);
      a1[4] = (short)f2bf(xb1.x); a1[5] = (short)f2bf(xb1.y);
      a1[6] = (short)f2bf(xb1.z); a1[7] = (short)f2bf(xb1.w);
      const u16* bp = w1t + (size_t)(kc * 2 + h2) * 8192
                          + (size_t)(wc2 * 8) * 512 + (cl * 4 + q) * 8;
#pragma unroll
      for (int nt = 0; nt < 8; ++nt) {
        bfrag bfr = *(const bfrag*)(bp + nt * 512);
        // swapped: D = W1^T x^T -> lane (cl,q), reg r = h[tok=..+cl][c=nt16+q*4+r]
        acc1[0][nt] = __builtin_amdgcn_mfma_f32_16x16x32_bf16(bfr, a0, acc1[0][nt], 0, 0, 0);
        acc1[1][nt] = __builtin_amdgcn_mfma_f32_16x16x32_bf16(bfr, a1, acc1[1][nt], 0, 0, 0);
      }
    }
  }
  // write h (+b1) to LDS as bf16: 4 consecutive cols per lane -> ds_write_b64
#pragma unroll
  for (int mm = 0; mm < 2; ++mm)
#pragma unroll
    for (int nt = 0; nt < 8; ++nt) {
      const int c0 = wc2 * 128 + nt * 16 + q * 4;
      f32x4v bb = *(const f32x4v*)(b1 + c0);
      u32x2 pk;
      pk.x = (u32)f2bf(acc1[mm][nt][0] + bb.x) | ((u32)f2bf(acc1[mm][nt][1] + bb.y) << 16);
      pk.y = (u32)f2bf(acc1[mm][nt][2] + bb.z) | ((u32)f2bf(acc1[mm][nt][3] + bb.w) << 16);
      *(u32x2*)&hs[rw * 32 + mm * 16 + cl][c0] = pk;
    }
  __syncthreads();

  // ---- stage 2: per-expert GEMM, SWAPPED operands -> f32x4 output stores ----
  const u16* wetw = wet + (size_t)(w * 2) * 512 + (size_t)(cl * 4 + q) * 8;
  bfrag pf0 = *(const bfrag*)(wetw);            // flattened (e,s)=0 prefetch
  bfrag pf1 = *(const bfrag*)(wetw + 512);
  for (int e = 0; e < 4; ++e) {
    const int cnt  = cnt_s[e];             // block-uniform
    const int ng   = (cnt + 15) >> 4;      // <= 8
    const int base = base_s[e];
    const int pb   = (base < BM) ? base : (BM - 1);   // cnt==0 edge safety

    int  prow_r[8];
    bool val_r[8];
#pragma unroll
    for (int g = 0; g < 8; ++g) {
      const int rowi = g * 16 + cl;
      val_r[g]  = rowi < cnt;
      prow_r[g] = perm_s[val_r[g] ? (base + rowi) : pb];
    }

    facc acc2[8][2];
#pragma unroll
    for (int g = 0; g < 8; ++g) {
      acc2[g][0] = (facc){0.f, 0.f, 0.f, 0.f};
      acc2[g][1] = (facc){0.f, 0.f, 0.f, 0.f};
    }

#pragma unroll
    for (int s = 0; s < 8; ++s) {
      const int k0 = s * 32 + q * 8;
      bfrag wf0 = pf0, wf1 = pf1;
      const int f = e * 8 + s;
      if (f < 31) {                         // prefetch next flattened step
        pf0 = *(const bfrag*)(wetw + (size_t)(f + 1) * 8192);
        pf1 = *(const bfrag*)(wetw + (size_t)(f + 1) * 8192 + 512);
      }
#pragma unroll
      for (int g = 0; g < 8; ++g) {
        if (g < ng) {
          bfrag a = *(const bfrag*)&hs[prow_r[g]][k0];
          // swapped: D = We^T h^T -> lane (cl,q), reg r = y[tok_cl][c0+q*4+r]
          acc2[g][0] = __builtin_amdgcn_mfma_f32_16x16x32_bf16(wf0, a, acc2[g][0], 0, 0, 0);
          acc2[g][1] = __builtin_amdgcn_mfma_f32_16x16x32_bf16(wf1, a, acc2[g][1], 0, 0, 0);
        }
      }
    }
    // epilogue: out = gate * (acc + be[e]) — two 16B stores per g
    {
      const int c0 = w * 32 + q * 4;
      f32x4v bev0 = *(const f32x4v*)(be + e * 256 + c0);
      f32x4v bev1 = *(const f32x4v*)(be + e * 256 + c0 + 16);
#pragma unroll
      for (int g = 0; g < 8; ++g) {
        if (g < ng && val_r[g]) {
          const int tok = prow_r[g];
          const float gate = gate_s[tok];
          float* orow = out + (size_t)(tokbase + tok) * HD + c0;
          f32x4v o0, o1;
          o0.x = gate * (acc2[g][0][0] + bev0.x);
          o0.y = gate * (acc2[g][0][1] + bev0.y);
          o0.z = gate * (acc2[g][0][2] + bev0.z);
          o0.w = gate * (acc2[g][0][3] + bev0.w);
          o1.x = gate * (acc2[g][1][0] + bev1.x);
          o1.y = gate * (acc2[g][1][1] + bev1.y);
          o1.z = gate * (acc2[g][1][2] + bev1.z);
          o1.w = gate * (acc2[g][1][3] + bev1.w);
          *(f32x4v*)orow        = o0;
          *(f32x4v*)(orow + 16) = o1;
        }
      }
    }
  }
}

extern "C" void kernel_launch(void* const* d_in, const int* in_sizes, int n_in,
                              void* d_out, int out_size, void* d_ws, size_t ws_size,
                              hipStream_t stream) {
  const float* x  = (const float*)d_in[0];
  const float* W1 = (const float*)d_in[1];
  const float* b1 = (const float*)d_in[2];
  const float* Wg = (const float*)d_in[3];
  const float* We = (const float*)d_in[4];
  const float* be = (const float*)d_in[5];
  float* out = (float*)d_out;

  char* ws = (char*)d_ws;
  u16*   w1t   = (u16*)(ws + WS_W1T);
  u16*   wet   = (u16*)(ws + WS_WET);
  float* wcomb = (float*)(ws + WS_WCOMB);
  float* bcomb = (float*)(ws + WS_BCOMB);
  unsigned long long* flag = (unsigned long long*)(ws + WS_FLAG);

  prep_all <<<417, 256, 0, stream>>>(W1, b1, Wg, We, w1t, wet, wcomb, bcomb, flag);
  moe_fused<<<NBLK, 512, 0, stream>>>(x, w1t, wet, wcomb, bcomb, b1, be, out, flag);
}